// Round 1
// baseline (50.992 us; speedup 1.0000x reference)
//
#include <hip/hip_runtime.h>
#include <math.h>

#define B_ 4
#define C_ 32
#define H_ 256
#define W_ 256
#define HW_ (H_ * W_)
#define K_ 9
#define EPS_ 1e-12f

__global__ __launch_bounds__(256) void asfr_kernel(const float* __restrict__ fe,
                                                   const float* __restrict__ fu,
                                                   float* __restrict__ out) {
    int idx = blockIdx.x * blockDim.x + threadIdx.x;   // [0, B*H*W)
    int n = idx & (HW_ - 1);
    int b = idx >> 16;                                  // HW_ = 2^16
    int h = n >> 8;
    int w = n & (W_ - 1);

    int base = b * (C_ * HW_) + n;                      // max ~8.4M, fits int

    int off[K_];
    bool valid[K_];
#pragma unroll
    for (int k = 0; k < K_; ++k) {
        int di = k / 3 - 1, dj = k % 3 - 1;
        off[k] = di * W_ + dj;
        valid[k] = ((unsigned)(h + di) < (unsigned)H_) && ((unsigned)(w + dj) < (unsigned)W_);
    }

    float dot[K_], psq[K_], dsq[K_];
#pragma unroll
    for (int k = 0; k < K_; ++k) { dot[k] = 0.f; psq[k] = 0.f; dsq[k] = 0.f; }
    float fsq = 0.f;

    // Pass 1: accumulate per-k statistics over channels
    for (int c = 0; c < C_; ++c) {
        int a = base + c * HW_;
        float f = fe[a];
        fsq += f * f;
#pragma unroll
        for (int k = 0; k < K_; ++k) {
            float p = valid[k] ? fu[a + off[k]] : 0.f;
            dot[k] += p * f;
            psq[k] += p * p;
            float d = p - f;
            dsq[k] += d * d;
        }
    }

    float nf = fmaxf(sqrtf(fsq), EPS_);

    float cosv[K_], negd[K_];
#pragma unroll
    for (int k = 0; k < K_; ++k) {
        float np = fmaxf(sqrtf(psq[k]), EPS_);
        cosv[k] = dot[k] / (np * nf);
        negd[k] = -sqrtf(dsq[k]);
    }

    // softmax over k for cosine and for -dist
    float m1 = cosv[0], m2 = negd[0];
#pragma unroll
    for (int k = 1; k < K_; ++k) {
        m1 = fmaxf(m1, cosv[k]);
        m2 = fmaxf(m2, negd[k]);
    }
    float e1[K_], e2[K_], s1 = 0.f, s2 = 0.f;
#pragma unroll
    for (int k = 0; k < K_; ++k) {
        e1[k] = __expf(cosv[k] - m1);
        e2[k] = __expf(negd[k] - m2);
        s1 += e1[k];
        s2 += e2[k];
    }
    float r1 = 0.5f / s1, r2 = 0.5f / s2;
    float wt[K_];
#pragma unroll
    for (int k = 0; k < K_; ++k) wt[k] = e1[k] * r1 + e2[k] * r2;

    // Pass 2: weighted gather + residual
    for (int c = 0; c < C_; ++c) {
        int a = base + c * HW_;
        float acc = fe[a];
#pragma unroll
        for (int k = 0; k < K_; ++k) {
            float p = valid[k] ? fu[a + off[k]] : 0.f;
            acc = fmaf(wt[k], p, acc);
        }
        out[a] = acc;
    }
}

extern "C" void kernel_launch(void* const* d_in, const int* in_sizes, int n_in,
                              void* d_out, int out_size, void* d_ws, size_t ws_size,
                              hipStream_t stream) {
    const float* fe = (const float*)d_in[0];
    const float* fu = (const float*)d_in[1];
    float* out = (float*)d_out;
    int total = B_ * H_ * W_;
    dim3 grid(total / 256), block(256);
    hipLaunchKernelGGL(asfr_kernel, grid, block, 0, stream, fe, fu, out);
}